// Round 1
// baseline (239.431 us; speedup 1.0000x reference)
//
#include <hip/hip_runtime.h>
#include <stdint.h>

typedef unsigned short u16t;
typedef __attribute__((ext_vector_type(8))) short bf16x8;
typedef __attribute__((ext_vector_type(4))) float f32x4;

#define DEV __device__ __forceinline__

DEV u16t f2bf(float f) {
  union { float f; unsigned u; } v; v.f = f;
  unsigned r = v.u + 0x7FFFu + ((v.u >> 16) & 1u);
  return (u16t)(r >> 16);
}

DEV void glds16(const void* g, void* l) {
  __builtin_amdgcn_global_load_lds((const __attribute__((address_space(1))) void*)g,
                                   (__attribute__((address_space(3))) void*)l, 16, 0, 0);
}

// ---------------- cast x: f32 -> bf16, 8 elems/thread ----------------
__global__ __launch_bounds__(256) void k_cast_x(const float* __restrict__ x,
                                                u16t* __restrict__ xb, int n) {
  int i = (blockIdx.x * 256 + threadIdx.x) * 8;
  if (i >= n) return;
  const float4* p = (const float4*)(x + i);
  float4 a = p[0], b = p[1];
  union { u16t h[8]; int4 v; } o;
  o.h[0] = f2bf(a.x); o.h[1] = f2bf(a.y); o.h[2] = f2bf(a.z); o.h[3] = f2bf(a.w);
  o.h[4] = f2bf(b.x); o.h[5] = f2bf(b.y); o.h[6] = f2bf(b.z); o.h[7] = f2bf(b.w);
  *(int4*)(xb + i) = o.v;
}

// ------- transpose + cast: src[R][C] f32 -> dst[C][R] bf16, 64x64 tiles -------
__global__ __launch_bounds__(256) void k_transpose_cast(const float* __restrict__ src,
                                                        u16t* __restrict__ dst,
                                                        int R, int C) {
  __shared__ u16t tile[64][65];
  int c0 = blockIdx.x * 64, r0 = blockIdx.y * 64;
  int tid = threadIdx.x;
#pragma unroll
  for (int i = 0; i < 16; i++) {
    int idx = tid + i * 256;
    int r = idx >> 6, c = idx & 63;
    tile[c][r] = f2bf(src[(size_t)(r0 + r) * C + (c0 + c)]);
  }
  __syncthreads();
#pragma unroll
  for (int i = 0; i < 16; i++) {
    int idx = tid + i * 256;
    int rr = idx >> 6, cc = idx & 63;
    dst[(size_t)(c0 + rr) * R + (r0 + cc)] = tile[rr][cc];
  }
}

// ---------------- shared GEMM mainloop: C = A[M,K] * Bt[N,K]^T ----------------
// 256 thr = 4 waves (2x2), wave tile 64x64, block tile 128x128, BK=32.
template <int K>
DEV void gemm_mainloop(const u16t* __restrict__ A, const u16t* __restrict__ Bt,
                       int m0, int n0, u16t* ldsA, u16t* ldsB, f32x4 acc[4][4]) {
  const int tid = threadIdx.x;
  const int lane = tid & 63;
  const int wid = tid >> 6;
  const int wm = wid >> 1, wn = wid & 1;
#pragma unroll
  for (int i = 0; i < 4; i++)
#pragma unroll
    for (int j = 0; j < 4; j++) acc[i][j] = f32x4{0.f, 0.f, 0.f, 0.f};

  char* lA = (char*)ldsA;
  char* lB = (char*)ldsB;

  for (int k0 = 0; k0 < K; k0 += 32) {
    // stage 128x32 bf16 tiles of A and Bt (512 granules x 16B each)
#pragma unroll
    for (int j = 0; j < 2; j++) {
      int g = wid * 64 + lane + j * 256;
      int row = g >> 2;          // 4 granules per 64B row
      int cb = (g & 3) * 16;     // byte offset in row
      glds16((const char*)(A + (size_t)(m0 + row) * K + k0) + cb,
             lA + j * 4096 + wid * 1024);
      glds16((const char*)(Bt + (size_t)(n0 + row) * K + k0) + cb,
             lB + j * 4096 + wid * 1024);
    }
    __syncthreads();
    bf16x8 af[4], bfr[4];
    const int lr = lane & 15;
    const int ko = (lane >> 4) * 8;
#pragma unroll
    for (int f = 0; f < 4; f++) {
      af[f]  = *(const bf16x8*)(ldsA + (wm * 64 + f * 16 + lr) * 32 + ko);
      bfr[f] = *(const bf16x8*)(ldsB + (wn * 64 + f * 16 + lr) * 32 + ko);
    }
#pragma unroll
    for (int i = 0; i < 4; i++)
#pragma unroll
      for (int j = 0; j < 4; j++)
        acc[i][j] = __builtin_amdgcn_mfma_f32_16x16x32_bf16(af[i], bfr[j], acc[i][j], 0, 0, 0);
    __syncthreads();
  }
}

// ---------------- GEMM1: qkv = xb @ WqkvT^T + b, scatter to q/k/vt ----------------
// q,k: [BH][T][64] bf16 ; vt: [BH][64][T] bf16 (V transposed)
__global__ __launch_bounds__(256) void k_gemm_qkv(const u16t* __restrict__ xb,
                                                  const u16t* __restrict__ wt,
                                                  const float* __restrict__ bias,
                                                  u16t* __restrict__ q,
                                                  u16t* __restrict__ kk,
                                                  u16t* __restrict__ vt) {
  __shared__ u16t ldsA[128 * 32];
  __shared__ u16t ldsB[128 * 32];
  __shared__ u16t ldsE[4][64 * 64];
  const int m0 = blockIdx.x * 128, n0 = blockIdx.y * 128;
  f32x4 acc[4][4];
  gemm_mainloop<1024>(xb, wt, m0, n0, ldsA, ldsB, acc);

  const int lane = threadIdx.x & 63, wid = threadIdx.x >> 6;
  const int wm = wid >> 1, wn = wid & 1;
  const int nbase = n0 + wn * 64;       // 64-aligned -> exactly one head block
  const int which = nbase >> 10;        // 0=q 1=k 2=v
  const int hb = (nbase & 1023) >> 6;   // head
  const int bb = m0 >> 11;              // batch
  const int t0 = (m0 & 2047) + wm * 64;
  const int bh = bb * 16 + hb;
  u16t* eb = ldsE[wid];                 // per-wave 64x64 staging (wave-internal)
#pragma unroll
  for (int fm = 0; fm < 4; fm++) {
#pragma unroll
    for (int fn = 0; fn < 4; fn++) {
      float bv = bias[nbase + fn * 16 + (lane & 15)];
#pragma unroll
      for (int i = 0; i < 4; i++) {
        int t_loc = fm * 16 + (lane >> 4) * 4 + i;
        int d_loc = fn * 16 + (lane & 15);
        float v = acc[fm][fn][i] + bv;
        if (which == 2) eb[d_loc * 64 + t_loc] = f2bf(v);   // transposed for V
        else            eb[t_loc * 64 + d_loc] = f2bf(v);
      }
    }
  }
  asm volatile("s_waitcnt lgkmcnt(0)" ::: "memory");  // wave-internal LDS bounce
  u16t* dst;
  size_t base, rowstride;
  if (which == 2) { dst = vt; base = (size_t)bh * 64 * 2048 + t0; rowstride = 2048; }
  else { dst = (which == 0) ? q : kk; base = ((size_t)bh * 2048 + t0) * 64; rowstride = 64; }
#pragma unroll
  for (int it = 0; it < 8; it++) {
    int g = it * 64 + lane;
    int r = g >> 3;
    int ce = (g & 7) * 8;   // element offset in row
    *(int4*)(dst + base + (size_t)r * rowstride + ce) = *(const int4*)(eb + r * 64 + ce);
  }
}

// ---------------- flash attention, causal ----------------
// grid (qtile=32, bh=32); 4 waves, wave = 16 q-rows; KV tile = 64
__global__ __launch_bounds__(256) void k_attn(const u16t* __restrict__ q,
                                              const u16t* __restrict__ kk,
                                              const u16t* __restrict__ vt,
                                              u16t* __restrict__ attn) {
  __shared__ u16t ldsK[64 * 64];   // [kv][d]
  __shared__ u16t ldsV[64 * 64];   // [d][kv]
  __shared__ u16t ldsP[4][16 * 64];
  const int qi = blockIdx.x;
  const int bh = blockIdx.y;
  const int lane = threadIdx.x & 63, wid = threadIdx.x >> 6;
  const size_t hbase = (size_t)bh * 2048 * 64;
  const size_t vbase = (size_t)bh * 64 * 2048;
  const float NINF = -__builtin_inff();
  const float LOG2E = 1.44269504088896f;

  bf16x8 qf[2];
  {
    const int qrow = qi * 64 + wid * 16 + (lane & 15);
    const u16t* qp = q + hbase + (size_t)qrow * 64 + (lane >> 4) * 8;
#pragma unroll
    for (int ks = 0; ks < 2; ks++) qf[ks] = *(const bf16x8*)(qp + ks * 32);
  }

  f32x4 o[4];
#pragma unroll
  for (int i = 0; i < 4; i++) o[i] = f32x4{0.f, 0.f, 0.f, 0.f};
  float m_run[4] = {NINF, NINF, NINF, NINF};
  float l_run[4] = {0.f, 0.f, 0.f, 0.f};
  char* lK = (char*)ldsK;
  char* lV = (char*)ldsV;
  u16t* pb = ldsP[wid];

  for (int kt = 0; kt <= qi; kt++) {
#pragma unroll
    for (int j = 0; j < 2; j++) {
      int g = wid * 64 + lane + j * 256;
      int r = g >> 3;
      int cb = (g & 7) * 16;
      glds16((const char*)(kk + hbase + (size_t)(kt * 64 + r) * 64) + cb,
             lK + j * 4096 + wid * 1024);
      glds16((const char*)(vt + vbase + (size_t)r * 2048 + kt * 64) + cb,
             lV + j * 4096 + wid * 1024);
    }
    __syncthreads();

    // S = Q K^T, scaled 1/sqrt(64)
    float sv[4][4];
#pragma unroll
    for (int f = 0; f < 4; f++) {
      f32x4 s = f32x4{0.f, 0.f, 0.f, 0.f};
#pragma unroll
      for (int ks = 0; ks < 2; ks++) {
        bf16x8 kf = *(const bf16x8*)(ldsK + (f * 16 + (lane & 15)) * 64 + ks * 32 + (lane >> 4) * 8);
        s = __builtin_amdgcn_mfma_f32_16x16x32_bf16(qf[ks], kf, s, 0, 0, 0);
      }
#pragma unroll
      for (int i = 0; i < 4; i++) sv[f][i] = s[i] * 0.125f;
    }
    if (kt == qi) {  // diagonal tile: mask local kv col > local q row
#pragma unroll
      for (int f = 0; f < 4; f++) {
        int kvc = f * 16 + (lane & 15);
#pragma unroll
        for (int i = 0; i < 4; i++) {
          int qr = wid * 16 + (lane >> 4) * 4 + i;
          if (kvc > qr) sv[f][i] = NINF;
        }
      }
    }
    // online softmax: rows live in reg i across 16-lane groups x 4 frags
    float pv[4][4];
#pragma unroll
    for (int i = 0; i < 4; i++) {
      float mx = fmaxf(fmaxf(sv[0][i], sv[1][i]), fmaxf(sv[2][i], sv[3][i]));
#pragma unroll
      for (int off = 1; off < 16; off <<= 1) mx = fmaxf(mx, __shfl_xor(mx, off));
      float mnew = fmaxf(m_run[i], mx);
      float al = exp2f((m_run[i] - mnew) * LOG2E);
      m_run[i] = mnew;
      float ssum = 0.f;
#pragma unroll
      for (int f = 0; f < 4; f++) {
        float p = exp2f((sv[f][i] - mnew) * LOG2E);
        pv[f][i] = p;
        ssum += p;
      }
#pragma unroll
      for (int off = 1; off < 16; off <<= 1) ssum += __shfl_xor(ssum, off);
      l_run[i] = l_run[i] * al + ssum;
#pragma unroll
      for (int df = 0; df < 4; df++) o[df][i] *= al;
    }
    // P (C-layout) -> per-wave LDS row-major [16][64] -> A-layout frags
#pragma unroll
    for (int f = 0; f < 4; f++)
#pragma unroll
      for (int i = 0; i < 4; i++)
        pb[((lane >> 4) * 4 + i) * 64 + f * 16 + (lane & 15)] = f2bf(pv[f][i]);
    asm volatile("s_waitcnt lgkmcnt(0)" ::: "memory");
    // O += P @ V   (B-operand = VT rows)
#pragma unroll
    for (int ks = 0; ks < 2; ks++) {
      bf16x8 pf = *(const bf16x8*)(pb + (lane & 15) * 64 + ks * 32 + (lane >> 4) * 8);
#pragma unroll
      for (int df = 0; df < 4; df++) {
        bf16x8 vf = *(const bf16x8*)(ldsV + (df * 16 + (lane & 15)) * 64 + ks * 32 + (lane >> 4) * 8);
        o[df] = __builtin_amdgcn_mfma_f32_16x16x32_bf16(pf, vf, o[df], 0, 0, 0);
      }
    }
    __syncthreads();
  }

  const int bb = bh >> 4, h = bh & 15;
#pragma unroll
  for (int df = 0; df < 4; df++) {
#pragma unroll
    for (int i = 0; i < 4; i++) {
      int t = qi * 64 + wid * 16 + (lane >> 4) * 4 + i;
      int c = h * 64 + df * 16 + (lane & 15);
      attn[((size_t)bb * 2048 + t) * 1024 + c] = f2bf(o[df][i] / l_run[i]);
    }
  }
}

// ---------------- GEMM2: out = attn @ WoutT^T + b_out (fp32 out) ----------------
__global__ __launch_bounds__(256) void k_gemm_out(const u16t* __restrict__ attn,
                                                  const u16t* __restrict__ wt,
                                                  const float* __restrict__ bias,
                                                  float* __restrict__ out) {
  __shared__ u16t ldsA[128 * 32];
  __shared__ u16t ldsB[128 * 32];
  const int m0 = blockIdx.x * 128, n0 = blockIdx.y * 128;
  f32x4 acc[4][4];
  gemm_mainloop<1024>(attn, wt, m0, n0, ldsA, ldsB, acc);

  const int lane = threadIdx.x & 63, wid = threadIdx.x >> 6;
  const int wm = wid >> 1, wn = wid & 1;
#pragma unroll
  for (int fm = 0; fm < 4; fm++) {
    int row = m0 + wm * 64 + fm * 16 + (lane >> 4) * 4;
#pragma unroll
    for (int fn = 0; fn < 4; fn++) {
      int col = n0 + wn * 64 + fn * 16 + (lane & 15);
      float bv = bias[col];
#pragma unroll
      for (int i = 0; i < 4; i++)
        out[(size_t)(row + i) * 1024 + col] = acc[fm][fn][i] + bv;
    }
  }
}

extern "C" void kernel_launch(void* const* d_in, const int* in_sizes, int n_in,
                              void* d_out, int out_size, void* d_ws, size_t ws_size,
                              hipStream_t stream) {
  const float* x     = (const float*)d_in[0];
  const float* W_qkv = (const float*)d_in[1];
  const float* b_qkv = (const float*)d_in[2];
  const float* W_out = (const float*)d_in[3];
  const float* b_out = (const float*)d_in[4];
  float* out = (float*)d_out;

  char* ws = (char*)d_ws;
  u16t* xb    = (u16t*)(ws);                       // 4096x1024 bf16   (8 MB)
  u16t* wqkvT = (u16t*)(ws + 8388608);             // 3072x1024 bf16   (6 MB)
  u16t* woutT = (u16t*)(ws + 14680064);            // 1024x1024 bf16   (2 MB)
  u16t* qb    = (u16t*)(ws + 16777216);            // [32][2048][64]   (8 MB)
  u16t* kb    = (u16t*)(ws + 25165824);            // [32][2048][64]   (8 MB)
  u16t* vtb   = (u16t*)(ws + 33554432);            // [32][64][2048]   (8 MB)
  u16t* attnb = (u16t*)(ws + 41943040);            // 4096x1024 bf16   (8 MB)

  k_cast_x<<<2048, 256, 0, stream>>>(x, xb, 4194304);
  k_transpose_cast<<<dim3(48, 16), 256, 0, stream>>>(W_qkv, wqkvT, 1024, 3072);
  k_transpose_cast<<<dim3(16, 16), 256, 0, stream>>>(W_out, woutT, 1024, 1024);
  k_gemm_qkv<<<dim3(32, 24), 256, 0, stream>>>(xb, wqkvT, b_qkv, qb, kb, vtb);
  k_attn<<<dim3(32, 32), 256, 0, stream>>>(qb, kb, vtb, attnb);
  k_gemm_out<<<dim3(32, 8), 256, 0, stream>>>(attnb, woutT, b_out, out);
}

// Round 2
// 153.212 us; speedup vs baseline: 1.5627x; 1.5627x over previous
//
#include <hip/hip_runtime.h>
#include <stdint.h>

typedef unsigned short u16t;
typedef __attribute__((ext_vector_type(8))) short bf16x8;
typedef __attribute__((ext_vector_type(4))) float f32x4;

#define DEV __device__ __forceinline__

DEV u16t f2bf(float f) {
  union { float f; unsigned u; } v; v.f = f;
  unsigned r = v.u + 0x7FFFu + ((v.u >> 16) & 1u);
  return (u16t)(r >> 16);
}

DEV void glds16(const void* g, void* l) {
  __builtin_amdgcn_global_load_lds((const __attribute__((address_space(1))) void*)g,
                                   (__attribute__((address_space(3))) void*)l, 16, 0, 0);
}

// ---------------- cast x: f32 -> bf16, 8 elems/thread ----------------
__global__ __launch_bounds__(256) void k_cast_x(const float* __restrict__ x,
                                                u16t* __restrict__ xb, int n) {
  int i = (blockIdx.x * 256 + threadIdx.x) * 8;
  if (i >= n) return;
  const float4* p = (const float4*)(x + i);
  float4 a = p[0], b = p[1];
  union { u16t h[8]; int4 v; } o;
  o.h[0] = f2bf(a.x); o.h[1] = f2bf(a.y); o.h[2] = f2bf(a.z); o.h[3] = f2bf(a.w);
  o.h[4] = f2bf(b.x); o.h[5] = f2bf(b.y); o.h[6] = f2bf(b.z); o.h[7] = f2bf(b.w);
  *(int4*)(xb + i) = o.v;
}

// ------- transpose + cast: src[R][C] f32 -> dst[C][R] bf16, 64x64 tiles -------
__global__ __launch_bounds__(256) void k_transpose_cast(const float* __restrict__ src,
                                                        u16t* __restrict__ dst,
                                                        int R, int C) {
  __shared__ u16t tile[64][65];
  int c0 = blockIdx.x * 64, r0 = blockIdx.y * 64;
  int tid = threadIdx.x;
#pragma unroll
  for (int i = 0; i < 16; i++) {
    int idx = tid + i * 256;
    int r = idx >> 6, c = idx & 63;
    tile[c][r] = f2bf(src[(size_t)(r0 + r) * C + (c0 + c)]);
  }
  __syncthreads();
#pragma unroll
  for (int i = 0; i < 16; i++) {
    int idx = tid + i * 256;
    int rr = idx >> 6, cc = idx & 63;
    dst[(size_t)(c0 + rr) * R + (r0 + cc)] = tile[rr][cc];
  }
}

// ---------------- shared GEMM mainloop: C = A[M,K] * Bt[N,K]^T ----------------
// 256 thr = 4 waves (2x2), wave tile 64x64, block tile 128x128, BK=32.
template <int K>
DEV void gemm_mainloop(const u16t* __restrict__ A, const u16t* __restrict__ Bt,
                       int m0, int n0, u16t* ldsA, u16t* ldsB, f32x4 acc[4][4]) {
  const int tid = threadIdx.x;
  const int lane = tid & 63;
  const int wid = tid >> 6;
  const int wm = wid >> 1, wn = wid & 1;
#pragma unroll
  for (int i = 0; i < 4; i++)
#pragma unroll
    for (int j = 0; j < 4; j++) acc[i][j] = f32x4{0.f, 0.f, 0.f, 0.f};

  char* lA = (char*)ldsA;
  char* lB = (char*)ldsB;

  for (int k0 = 0; k0 < K; k0 += 32) {
    // stage 128x32 bf16 tiles of A and Bt (512 granules x 16B each)
#pragma unroll
    for (int j = 0; j < 2; j++) {
      int g = wid * 64 + lane + j * 256;
      int row = g >> 2;          // 4 granules per 64B row
      int cb = (g & 3) * 16;     // byte offset in row
      glds16((const char*)(A + (size_t)(m0 + row) * K + k0) + cb,
             lA + j * 4096 + wid * 1024);
      glds16((const char*)(Bt + (size_t)(n0 + row) * K + k0) + cb,
             lB + j * 4096 + wid * 1024);
    }
    __syncthreads();
    bf16x8 af[4], bfr[4];
    const int lr = lane & 15;
    const int ko = (lane >> 4) * 8;
#pragma unroll
    for (int f = 0; f < 4; f++) {
      af[f]  = *(const bf16x8*)(ldsA + (wm * 64 + f * 16 + lr) * 32 + ko);
      bfr[f] = *(const bf16x8*)(ldsB + (wn * 64 + f * 16 + lr) * 32 + ko);
    }
#pragma unroll
    for (int i = 0; i < 4; i++)
#pragma unroll
      for (int j = 0; j < 4; j++)
        acc[i][j] = __builtin_amdgcn_mfma_f32_16x16x32_bf16(af[i], bfr[j], acc[i][j], 0, 0, 0);
    __syncthreads();
  }
}

// ---------------- GEMM1: qkv = xb @ WqkvT^T + b, scatter to q/k/vt ----------------
// q,k: [BH][T][64] bf16 ; vt: [BH][64][T] bf16 (V transposed)
__global__ __launch_bounds__(256) void k_gemm_qkv(const u16t* __restrict__ xb,
                                                  const u16t* __restrict__ wt,
                                                  const float* __restrict__ bias,
                                                  u16t* __restrict__ q,
                                                  u16t* __restrict__ kk,
                                                  u16t* __restrict__ vt) {
  __shared__ u16t ldsA[128 * 32];
  __shared__ u16t ldsB[128 * 32];
  __shared__ u16t ldsE[4][64 * 64];
  const int m0 = blockIdx.x * 128, n0 = blockIdx.y * 128;
  f32x4 acc[4][4];
  gemm_mainloop<1024>(xb, wt, m0, n0, ldsA, ldsB, acc);

  const int lane = threadIdx.x & 63, wid = threadIdx.x >> 6;
  const int wm = wid >> 1, wn = wid & 1;
  const int nbase = n0 + wn * 64;       // 64-aligned -> exactly one head block
  const int which = nbase >> 10;        // 0=q 1=k 2=v
  const int hb = (nbase & 1023) >> 6;   // head
  const int bb = m0 >> 11;              // batch
  const int t0 = (m0 & 2047) + wm * 64;
  const int bh = bb * 16 + hb;
  u16t* eb = ldsE[wid];                 // per-wave 64x64 staging (wave-internal)
#pragma unroll
  for (int fm = 0; fm < 4; fm++) {
#pragma unroll
    for (int fn = 0; fn < 4; fn++) {
      float bv = bias[nbase + fn * 16 + (lane & 15)];
#pragma unroll
      for (int i = 0; i < 4; i++) {
        int t_loc = fm * 16 + (lane >> 4) * 4 + i;
        int d_loc = fn * 16 + (lane & 15);
        float v = acc[fm][fn][i] + bv;
        if (which == 2) eb[d_loc * 64 + t_loc] = f2bf(v);   // transposed for V
        else            eb[t_loc * 64 + d_loc] = f2bf(v);
      }
    }
  }
  asm volatile("s_waitcnt lgkmcnt(0)" ::: "memory");  // wave-internal LDS bounce
  u16t* dst;
  size_t base, rowstride;
  if (which == 2) { dst = vt; base = (size_t)bh * 64 * 2048 + t0; rowstride = 2048; }
  else { dst = (which == 0) ? q : kk; base = ((size_t)bh * 2048 + t0) * 64; rowstride = 64; }
#pragma unroll
  for (int it = 0; it < 8; it++) {
    int g = it * 64 + lane;
    int r = g >> 3;
    int ce = (g & 7) * 8;   // element offset in row
    *(int4*)(dst + base + (size_t)r * rowstride + ce) = *(const int4*)(eb + r * 64 + ce);
  }
}

// ---------------- flash attention, causal, paired q-tiles ----------------
// grid (pair=16, bh=32); 4 waves; block handles q-tiles lo=p and hi=31-p
// (lo+1) + (hi+1) = 33 kv-tile compute units per block -> perfectly balanced.
// K/V staged once per kv tile, consumed by both q-tiles. Double-buffered.
// All hot LDS tiles XOR-swizzled: phys_byte = row*128 + (c ^ ((row&7)<<4)).
__global__ __launch_bounds__(256) void k_attn(const u16t* __restrict__ q,
                                              const u16t* __restrict__ kk,
                                              const u16t* __restrict__ vt,
                                              u16t* __restrict__ attn) {
  __shared__ u16t ldsK[2][64 * 64];   // [kv][d] swizzled
  __shared__ u16t ldsV[2][64 * 64];   // [d][kv] swizzled
  __shared__ u16t ldsP[4][16 * 64];   // per-wave P, swizzled
  const int p = blockIdx.x;
  const int lo = p, hi = 31 - p;
  const int bh = blockIdx.y;
  const int lane = threadIdx.x & 63, wid = threadIdx.x >> 6;
  const int lr = lane & 15, lg = lane >> 4;
  const size_t hbase = (size_t)bh * 2048 * 64;
  const size_t vbase = (size_t)bh * 64 * 2048;
  const float NINF = -__builtin_inff();
  const float CEXP = 0.1803368801111204f;  // log2(e) / sqrt(64)

  // Q fragments for both tiles
  bf16x8 qlo[2], qhi[2];
  {
    const u16t* qp = q + hbase + (size_t)(lo * 64 + wid * 16 + lr) * 64 + lg * 8;
    const u16t* qp2 = q + hbase + (size_t)(hi * 64 + wid * 16 + lr) * 64 + lg * 8;
#pragma unroll
    for (int ks = 0; ks < 2; ks++) {
      qlo[ks] = *(const bf16x8*)(qp + ks * 32);
      qhi[ks] = *(const bf16x8*)(qp2 + ks * 32);
    }
  }

  f32x4 olo[4], ohi[4];
  float mlo[4], llo[4], mhi[4], lhi[4];
#pragma unroll
  for (int i = 0; i < 4; i++) {
    olo[i] = f32x4{0.f, 0.f, 0.f, 0.f};
    ohi[i] = f32x4{0.f, 0.f, 0.f, 0.f};
    mlo[i] = NINF; mhi[i] = NINF;
    llo[i] = 0.f;  lhi[i] = 0.f;
  }

  u16t* pb = ldsP[wid];

  auto stage = [&](int buf, int kt) {
#pragma unroll
    for (int j = 0; j < 2; j++) {
      int g = wid * 64 + lane + j * 256;
      int r = g >> 3;
      int cb = (g & 7) * 16;
      int sc = cb ^ ((r & 7) << 4);   // pre-swizzled source offset
      glds16((const char*)(kk + hbase + (size_t)(kt * 64 + r) * 64) + sc,
             (char*)ldsK[buf] + j * 4096 + wid * 1024);
      glds16((const char*)(vt + vbase + (size_t)r * 2048 + kt * 64) + sc,
             (char*)ldsV[buf] + j * 4096 + wid * 1024);
    }
  };

  auto compute = [&](int buf, bool diag, const bf16x8* qf, f32x4* o,
                     float* m_run, float* l_run) {
    const char* K = (const char*)ldsK[buf];
    const char* V = (const char*)ldsV[buf];
    float sv[4][4];
    __builtin_amdgcn_s_setprio(1);
#pragma unroll
    for (int f = 0; f < 4; f++) {
      f32x4 s = f32x4{0.f, 0.f, 0.f, 0.f};
#pragma unroll
      for (int ks = 0; ks < 2; ks++) {
        int row = f * 16 + lr;
        int cb = ks * 64 + lg * 16;
        bf16x8 kf = *(const bf16x8*)(K + row * 128 + (cb ^ ((row & 7) << 4)));
        s = __builtin_amdgcn_mfma_f32_16x16x32_bf16(qf[ks], kf, s, 0, 0, 0);
      }
#pragma unroll
      for (int i = 0; i < 4; i++) sv[f][i] = s[i];
    }
    __builtin_amdgcn_s_setprio(0);
    if (diag) {
#pragma unroll
      for (int f = 0; f < 4; f++) {
        int kvc = f * 16 + lr;
#pragma unroll
        for (int i = 0; i < 4; i++) {
          int qr = wid * 16 + lg * 4 + i;
          if (kvc > qr) sv[f][i] = NINF;
        }
      }
    }
    // online softmax on raw scores (scale folded into CEXP)
    float pvv[4][4];
#pragma unroll
    for (int i = 0; i < 4; i++) {
      float mx = fmaxf(fmaxf(sv[0][i], sv[1][i]), fmaxf(sv[2][i], sv[3][i]));
#pragma unroll
      for (int off = 1; off < 16; off <<= 1) mx = fmaxf(mx, __shfl_xor(mx, off));
      float mnew = fmaxf(m_run[i], mx);
      float al = exp2f((m_run[i] - mnew) * CEXP);
      m_run[i] = mnew;
      float ssum = 0.f;
#pragma unroll
      for (int f = 0; f < 4; f++) {
        float pp = exp2f((sv[f][i] - mnew) * CEXP);
        pvv[f][i] = pp;
        ssum += pp;
      }
#pragma unroll
      for (int off = 1; off < 16; off <<= 1) ssum += __shfl_xor(ssum, off);
      l_run[i] = l_run[i] * al + ssum;
#pragma unroll
      for (int df = 0; df < 4; df++) o[df][i] *= al;
    }
    // P -> per-wave LDS (swizzled write), then read as A-frags
#pragma unroll
    for (int f = 0; f < 4; f++)
#pragma unroll
      for (int i = 0; i < 4; i++) {
        int m = lg * 4 + i;
        int cby = (f * 32 + lr * 2) ^ ((m & 7) << 4);
        *(u16t*)((char*)pb + m * 128 + cby) = f2bf(pvv[f][i]);
      }
    asm volatile("s_waitcnt lgkmcnt(0)" ::: "memory");
    __builtin_amdgcn_s_setprio(1);
#pragma unroll
    for (int ks = 0; ks < 2; ks++) {
      int cb = ks * 64 + lg * 16;
      bf16x8 pf = *(const bf16x8*)((const char*)pb + lr * 128 + (cb ^ ((lr & 7) << 4)));
#pragma unroll
      for (int df = 0; df < 4; df++) {
        int vrow = df * 16 + lr;
        bf16x8 vf = *(const bf16x8*)(V + vrow * 128 + (cb ^ ((vrow & 7) << 4)));
        o[df] = __builtin_amdgcn_mfma_f32_16x16x32_bf16(pf, vf, o[df], 0, 0, 0);
      }
    }
    __builtin_amdgcn_s_setprio(0);
  };

  stage(0, 0);
  __syncthreads();
  for (int kt = 0; kt <= hi; kt++) {
    int cur = kt & 1;
    if (kt < hi) stage(cur ^ 1, kt + 1);     // prefetch next tile (overlapped)
    compute(cur, kt == hi, qhi, ohi, mhi, lhi);
    if (kt <= lo) compute(cur, kt == lo, qlo, olo, mlo, llo);
    __syncthreads();
  }

  const int bb = bh >> 4, h = bh & 15;
  auto epi = [&](int qt, const f32x4* o, const float* l_run) {
#pragma unroll
    for (int i = 0; i < 4; i++) {
      float rinv = 1.0f / l_run[i];
      int t = qt * 64 + wid * 16 + lg * 4 + i;
#pragma unroll
      for (int df = 0; df < 4; df++) {
        int c = h * 64 + df * 16 + lr;
        attn[((size_t)bb * 2048 + t) * 1024 + c] = f2bf(o[df][i] * rinv);
      }
    }
  };
  epi(lo, olo, llo);
  epi(hi, ohi, lhi);
}

// ---------------- GEMM2: out = attn @ WoutT^T + b_out (fp32 out) ----------------
__global__ __launch_bounds__(256) void k_gemm_out(const u16t* __restrict__ attn,
                                                  const u16t* __restrict__ wt,
                                                  const float* __restrict__ bias,
                                                  float* __restrict__ out) {
  __shared__ u16t ldsA[128 * 32];
  __shared__ u16t ldsB[128 * 32];
  const int m0 = blockIdx.x * 128, n0 = blockIdx.y * 128;
  f32x4 acc[4][4];
  gemm_mainloop<1024>(attn, wt, m0, n0, ldsA, ldsB, acc);

  const int lane = threadIdx.x & 63, wid = threadIdx.x >> 6;
  const int wm = wid >> 1, wn = wid & 1;
#pragma unroll
  for (int fm = 0; fm < 4; fm++) {
    int row = m0 + wm * 64 + fm * 16 + (lane >> 4) * 4;
#pragma unroll
    for (int fn = 0; fn < 4; fn++) {
      int col = n0 + wn * 64 + fn * 16 + (lane & 15);
      float bv = bias[col];
#pragma unroll
      for (int i = 0; i < 4; i++)
        out[(size_t)(row + i) * 1024 + col] = acc[fm][fn][i] + bv;
    }
  }
}

extern "C" void kernel_launch(void* const* d_in, const int* in_sizes, int n_in,
                              void* d_out, int out_size, void* d_ws, size_t ws_size,
                              hipStream_t stream) {
  const float* x     = (const float*)d_in[0];
  const float* W_qkv = (const float*)d_in[1];
  const float* b_qkv = (const float*)d_in[2];
  const float* W_out = (const float*)d_in[3];
  const float* b_out = (const float*)d_in[4];
  float* out = (float*)d_out;

  char* ws = (char*)d_ws;
  u16t* xb    = (u16t*)(ws);                       // 4096x1024 bf16   (8 MB)
  u16t* wqkvT = (u16t*)(ws + 8388608);             // 3072x1024 bf16   (6 MB)
  u16t* woutT = (u16t*)(ws + 14680064);            // 1024x1024 bf16   (2 MB)
  u16t* qb    = (u16t*)(ws + 16777216);            // [32][2048][64]   (8 MB)
  u16t* kb    = (u16t*)(ws + 25165824);            // [32][2048][64]   (8 MB)
  u16t* vtb   = (u16t*)(ws + 33554432);            // [32][64][2048]   (8 MB)
  u16t* attnb = (u16t*)(ws + 41943040);            // 4096x1024 bf16   (8 MB)

  k_cast_x<<<2048, 256, 0, stream>>>(x, xb, 4194304);
  k_transpose_cast<<<dim3(48, 16), 256, 0, stream>>>(W_qkv, wqkvT, 1024, 3072);
  k_transpose_cast<<<dim3(16, 16), 256, 0, stream>>>(W_out, woutT, 1024, 1024);
  k_gemm_qkv<<<dim3(32, 24), 256, 0, stream>>>(xb, wqkvT, b_qkv, qb, kb, vtb);
  k_attn<<<dim3(16, 32), 256, 0, stream>>>(qb, kb, vtb, attnb);
  k_gemm_out<<<dim3(32, 8), 256, 0, stream>>>(attnb, woutT, b_out, out);
}

// Round 3
// 133.188 us; speedup vs baseline: 1.7977x; 1.1503x over previous
//
#include <hip/hip_runtime.h>
#include <stdint.h>

typedef unsigned short u16t;
typedef __attribute__((ext_vector_type(8))) short bf16x8;
typedef __attribute__((ext_vector_type(4))) float f32x4;

#define DEV __device__ __forceinline__

DEV u16t f2bf(float f) {
  union { float f; unsigned u; } v; v.f = f;
  unsigned r = v.u + 0x7FFFu + ((v.u >> 16) & 1u);
  return (u16t)(r >> 16);
}

DEV void glds16(const void* g, void* l) {
  __builtin_amdgcn_global_load_lds((const __attribute__((address_space(1))) void*)g,
                                   (__attribute__((address_space(3))) void*)l, 16, 0, 0);
}

// ---------------- cast x: f32 -> bf16, 8 elems/thread ----------------
__global__ __launch_bounds__(256) void k_cast_x(const float* __restrict__ x,
                                                u16t* __restrict__ xb, int n) {
  int i = (blockIdx.x * 256 + threadIdx.x) * 8;
  if (i >= n) return;
  const float4* p = (const float4*)(x + i);
  float4 a = p[0], b = p[1];
  union { u16t h[8]; int4 v; } o;
  o.h[0] = f2bf(a.x); o.h[1] = f2bf(a.y); o.h[2] = f2bf(a.z); o.h[3] = f2bf(a.w);
  o.h[4] = f2bf(b.x); o.h[5] = f2bf(b.y); o.h[6] = f2bf(b.z); o.h[7] = f2bf(b.w);
  *(int4*)(xb + i) = o.v;
}

// ------- transpose + cast: src[R][C] f32 -> dst[C][R] bf16, 64x64 tiles -------
__global__ __launch_bounds__(256) void k_transpose_cast(const float* __restrict__ src,
                                                        u16t* __restrict__ dst,
                                                        int R, int C) {
  __shared__ u16t tile[64][65];
  int c0 = blockIdx.x * 64, r0 = blockIdx.y * 64;
  int tid = threadIdx.x;
#pragma unroll
  for (int i = 0; i < 16; i++) {
    int idx = tid + i * 256;
    int r = idx >> 6, c = idx & 63;
    tile[c][r] = f2bf(src[(size_t)(r0 + r) * C + (c0 + c)]);
  }
  __syncthreads();
#pragma unroll
  for (int i = 0; i < 16; i++) {
    int idx = tid + i * 256;
    int rr = idx >> 6, cc = idx & 63;
    dst[(size_t)(c0 + rr) * R + (r0 + cc)] = tile[rr][cc];
  }
}

// ---------------- shared GEMM mainloop: C = A[M,K] * Bt[N,K]^T ----------------
template <int K>
DEV void gemm_mainloop(const u16t* __restrict__ A, const u16t* __restrict__ Bt,
                       int m0, int n0, u16t* ldsA, u16t* ldsB, f32x4 acc[4][4]) {
  const int tid = threadIdx.x;
  const int lane = tid & 63;
  const int wid = tid >> 6;
  const int wm = wid >> 1, wn = wid & 1;
#pragma unroll
  for (int i = 0; i < 4; i++)
#pragma unroll
    for (int j = 0; j < 4; j++) acc[i][j] = f32x4{0.f, 0.f, 0.f, 0.f};

  char* lA = (char*)ldsA;
  char* lB = (char*)ldsB;

  for (int k0 = 0; k0 < K; k0 += 32) {
#pragma unroll
    for (int j = 0; j < 2; j++) {
      int g = wid * 64 + lane + j * 256;
      int row = g >> 2;
      int cb = (g & 3) * 16;
      glds16((const char*)(A + (size_t)(m0 + row) * K + k0) + cb,
             lA + j * 4096 + wid * 1024);
      glds16((const char*)(Bt + (size_t)(n0 + row) * K + k0) + cb,
             lB + j * 4096 + wid * 1024);
    }
    __syncthreads();
    bf16x8 af[4], bfr[4];
    const int lr = lane & 15;
    const int ko = (lane >> 4) * 8;
#pragma unroll
    for (int f = 0; f < 4; f++) {
      af[f]  = *(const bf16x8*)(ldsA + (wm * 64 + f * 16 + lr) * 32 + ko);
      bfr[f] = *(const bf16x8*)(ldsB + (wn * 64 + f * 16 + lr) * 32 + ko);
    }
#pragma unroll
    for (int i = 0; i < 4; i++)
#pragma unroll
      for (int j = 0; j < 4; j++)
        acc[i][j] = __builtin_amdgcn_mfma_f32_16x16x32_bf16(af[i], bfr[j], acc[i][j], 0, 0, 0);
    __syncthreads();
  }
}

// ---------------- GEMM1: qkv = xb @ WqkvT^T + b, scatter to q/k/vt ----------------
__global__ __launch_bounds__(256) void k_gemm_qkv(const u16t* __restrict__ xb,
                                                  const u16t* __restrict__ wt,
                                                  const float* __restrict__ bias,
                                                  u16t* __restrict__ q,
                                                  u16t* __restrict__ kk,
                                                  u16t* __restrict__ vt) {
  __shared__ u16t ldsA[128 * 32];
  __shared__ u16t ldsB[128 * 32];
  __shared__ u16t ldsE[4][64 * 64];
  const int m0 = blockIdx.x * 128, n0 = blockIdx.y * 128;
  f32x4 acc[4][4];
  gemm_mainloop<1024>(xb, wt, m0, n0, ldsA, ldsB, acc);

  const int lane = threadIdx.x & 63, wid = threadIdx.x >> 6;
  const int wm = wid >> 1, wn = wid & 1;
  const int nbase = n0 + wn * 64;
  const int which = nbase >> 10;
  const int hb = (nbase & 1023) >> 6;
  const int bb = m0 >> 11;
  const int t0 = (m0 & 2047) + wm * 64;
  const int bh = bb * 16 + hb;
  u16t* eb = ldsE[wid];
#pragma unroll
  for (int fm = 0; fm < 4; fm++) {
#pragma unroll
    for (int fn = 0; fn < 4; fn++) {
      float bv = bias[nbase + fn * 16 + (lane & 15)];
#pragma unroll
      for (int i = 0; i < 4; i++) {
        int t_loc = fm * 16 + (lane >> 4) * 4 + i;
        int d_loc = fn * 16 + (lane & 15);
        float v = acc[fm][fn][i] + bv;
        if (which == 2) eb[d_loc * 64 + t_loc] = f2bf(v);
        else            eb[t_loc * 64 + d_loc] = f2bf(v);
      }
    }
  }
  asm volatile("s_waitcnt lgkmcnt(0)" ::: "memory");
  u16t* dst;
  size_t base, rowstride;
  if (which == 2) { dst = vt; base = (size_t)bh * 64 * 2048 + t0; rowstride = 2048; }
  else { dst = (which == 0) ? q : kk; base = ((size_t)bh * 2048 + t0) * 64; rowstride = 64; }
#pragma unroll
  for (int it = 0; it < 8; it++) {
    int g = it * 64 + lane;
    int r = g >> 3;
    int ce = (g & 7) * 8;
    *(int4*)(dst + base + (size_t)r * rowstride + ce) = *(const int4*)(eb + r * 64 + ce);
  }
}

// ---------------- flash attention, causal, paired q-tiles, swapped MFMA ------
// grid (pair=16, bh=32); 4 waves; block handles q-tiles lo=p and hi=31-p.
// QK^T computed swapped -> S^T: lane holds 16 kv values for ONE q (q=lane&15).
// Softmax: lane-local reduce + 2 shfl. PV swapped -> O^T: rescale lane-local.
__global__ __launch_bounds__(256) void k_attn(const u16t* __restrict__ q,
                                              const u16t* __restrict__ kk,
                                              const u16t* __restrict__ vt,
                                              u16t* __restrict__ attn) {
  __shared__ u16t ldsK[2][64 * 64];   // [kv][d] swizzled
  __shared__ u16t ldsV[2][64 * 64];   // [d][kv] swizzled
  __shared__ u16t ldsP[4][16 * 64];   // per-wave P[q][kv], swizzled
  const int p = blockIdx.x;
  const int lo = p, hi = 31 - p;
  const int bh = blockIdx.y;
  const int lane = threadIdx.x & 63, wid = threadIdx.x >> 6;
  const int lr = lane & 15, lg = lane >> 4;
  const size_t hbase = (size_t)bh * 2048 * 64;
  const size_t vbase = (size_t)bh * 64 * 2048;
  const float NINF = -__builtin_inff();
  const float CEXP = 0.1803368801111204f;  // log2(e) / sqrt(64)

  bf16x8 qlo[2], qhi[2];
  {
    const u16t* qp  = q + hbase + (size_t)(lo * 64 + wid * 16 + lr) * 64 + lg * 8;
    const u16t* qp2 = q + hbase + (size_t)(hi * 64 + wid * 16 + lr) * 64 + lg * 8;
#pragma unroll
    for (int ks = 0; ks < 2; ks++) {
      qlo[ks] = *(const bf16x8*)(qp + ks * 32);
      qhi[ks] = *(const bf16x8*)(qp2 + ks * 32);
    }
  }

  f32x4 olo[4], ohi[4];
#pragma unroll
  for (int i = 0; i < 4; i++) {
    olo[i] = f32x4{0.f, 0.f, 0.f, 0.f};
    ohi[i] = f32x4{0.f, 0.f, 0.f, 0.f};
  }
  float mlo = NINF, llo = 0.f, mhi = NINF, lhi = 0.f;

  u16t* pb = ldsP[wid];

  auto stage = [&](int buf, int kt) {
#pragma unroll
    for (int j = 0; j < 2; j++) {
      int g = wid * 64 + lane + j * 256;
      int r = g >> 3;
      int cb = (g & 7) * 16;
      int sc = cb ^ ((r & 7) << 4);
      glds16((const char*)(kk + hbase + (size_t)(kt * 64 + r) * 64) + sc,
             (char*)ldsK[buf] + j * 4096 + wid * 1024);
      glds16((const char*)(vt + vbase + (size_t)r * 2048 + kt * 64) + sc,
             (char*)ldsV[buf] + j * 4096 + wid * 1024);
    }
  };

  auto compute = [&](int buf, bool diag, const bf16x8* qf, f32x4* o,
                     float& m_run, float& l_run) {
    const char* K = (const char*)ldsK[buf];
    const char* V = (const char*)ldsV[buf];
    float sv[4][4];   // sv[f][i] = S^T[kv = 16f + 4lg + i][q = lr]
    __builtin_amdgcn_s_setprio(1);
#pragma unroll
    for (int f = 0; f < 4; f++) {
      f32x4 s = f32x4{0.f, 0.f, 0.f, 0.f};
#pragma unroll
      for (int ks = 0; ks < 2; ks++) {
        int row = f * 16 + lr;
        int cb = ks * 64 + lg * 16;
        bf16x8 kf = *(const bf16x8*)(K + row * 128 + (cb ^ ((row & 7) << 4)));
        s = __builtin_amdgcn_mfma_f32_16x16x32_bf16(kf, qf[ks], s, 0, 0, 0);
      }
#pragma unroll
      for (int i = 0; i < 4; i++) sv[f][i] = s[i];
    }
    __builtin_amdgcn_s_setprio(0);
    if (diag) {
      int qr = wid * 16 + lr;
#pragma unroll
      for (int f = 0; f < 4; f++)
#pragma unroll
        for (int i = 0; i < 4; i++)
          if (f * 16 + lg * 4 + i > qr) sv[f][i] = NINF;
    }
    // lane-local row max over 16 kv + 2 cross-group shuffles
    float mx = sv[0][0];
#pragma unroll
    for (int f = 0; f < 4; f++)
#pragma unroll
      for (int i = 0; i < 4; i++) mx = fmaxf(mx, sv[f][i]);
    mx = fmaxf(mx, __shfl_xor(mx, 16));
    mx = fmaxf(mx, __shfl_xor(mx, 32));
    float mnew = fmaxf(m_run, mx);
    float al = exp2f((m_run - mnew) * CEXP);
    m_run = mnew;
    float ssum = 0.f;
    u16t ph[4][4];
#pragma unroll
    for (int f = 0; f < 4; f++)
#pragma unroll
      for (int i = 0; i < 4; i++) {
        float pp = exp2f((sv[f][i] - mnew) * CEXP);
        ssum += pp;
        ph[f][i] = f2bf(pp);
      }
    ssum += __shfl_xor(ssum, 16);
    ssum += __shfl_xor(ssum, 32);
    l_run = l_run * al + ssum;
#pragma unroll
    for (int df = 0; df < 4; df++)
#pragma unroll
      for (int i = 0; i < 4; i++) o[df][i] *= al;
    // P[q=lr][kv]: 4 consecutive kv per (f) -> packed 8B swizzled writes
#pragma unroll
    for (int f = 0; f < 4; f++) {
      union { u16t h[4]; uint2 v; } pk;
      pk.h[0] = ph[f][0]; pk.h[1] = ph[f][1];
      pk.h[2] = ph[f][2]; pk.h[3] = ph[f][3];
      int cby = (f * 32 + lg * 8) ^ ((lr & 7) << 4);
      *(uint2*)((char*)pb + lr * 128 + cby) = pk.v;
    }
    asm volatile("s_waitcnt lgkmcnt(0)" ::: "memory");
    __builtin_amdgcn_s_setprio(1);
#pragma unroll
    for (int ks = 0; ks < 2; ks++) {
      int cb = ks * 64 + lg * 16;
      bf16x8 pf = *(const bf16x8*)((const char*)pb + lr * 128 + (cb ^ ((lr & 7) << 4)));
#pragma unroll
      for (int df = 0; df < 4; df++) {
        int vrow = df * 16 + lr;
        bf16x8 vf = *(const bf16x8*)(V + vrow * 128 + (cb ^ ((vrow & 7) << 4)));
        o[df] = __builtin_amdgcn_mfma_f32_16x16x32_bf16(vf, pf, o[df], 0, 0, 0);
      }
    }
    __builtin_amdgcn_s_setprio(0);
  };

  stage(0, 0);
  __syncthreads();
  for (int kt = 0; kt <= hi; kt++) {
    int cur = kt & 1;
    if (kt < hi) stage(cur ^ 1, kt + 1);
    compute(cur, kt == hi, qhi, ohi, mhi, lhi);
    if (kt <= lo) compute(cur, kt == lo, qlo, olo, mlo, llo);
    __syncthreads();
  }

  const int bb = bh >> 4, h = bh & 15;
  auto epi = [&](int qt, const f32x4* o, float l_run) {
    float rinv = 1.0f / l_run;
    int t = qt * 64 + wid * 16 + lr;
    size_t rowb = ((size_t)bb * 2048 + t) * 1024 + h * 64;
#pragma unroll
    for (int df = 0; df < 4; df++) {
      union { u16t h4[4]; uint2 v; } pk;
#pragma unroll
      for (int i = 0; i < 4; i++) pk.h4[i] = f2bf(o[df][i] * rinv);
      *(uint2*)(attn + rowb + df * 16 + lg * 4) = pk.v;
    }
  };
  epi(lo, olo, llo);
  epi(hi, ohi, lhi);
}

// ---------------- GEMM2: out = attn @ WoutT^T + b_out (fp32 out) ----------------
__global__ __launch_bounds__(256) void k_gemm_out(const u16t* __restrict__ attn,
                                                  const u16t* __restrict__ wt,
                                                  const float* __restrict__ bias,
                                                  float* __restrict__ out) {
  __shared__ u16t ldsA[128 * 32];
  __shared__ u16t ldsB[128 * 32];
  const int m0 = blockIdx.x * 128, n0 = blockIdx.y * 128;
  f32x4 acc[4][4];
  gemm_mainloop<1024>(attn, wt, m0, n0, ldsA, ldsB, acc);

  const int lane = threadIdx.x & 63, wid = threadIdx.x >> 6;
  const int wm = wid >> 1, wn = wid & 1;
#pragma unroll
  for (int fm = 0; fm < 4; fm++) {
    int row = m0 + wm * 64 + fm * 16 + (lane >> 4) * 4;
#pragma unroll
    for (int fn = 0; fn < 4; fn++) {
      int col = n0 + wn * 64 + fn * 16 + (lane & 15);
      float bv = bias[col];
#pragma unroll
      for (int i = 0; i < 4; i++)
        out[(size_t)(row + i) * 1024 + col] = acc[fm][fn][i] + bv;
    }
  }
}

extern "C" void kernel_launch(void* const* d_in, const int* in_sizes, int n_in,
                              void* d_out, int out_size, void* d_ws, size_t ws_size,
                              hipStream_t stream) {
  const float* x     = (const float*)d_in[0];
  const float* W_qkv = (const float*)d_in[1];
  const float* b_qkv = (const float*)d_in[2];
  const float* W_out = (const float*)d_in[3];
  const float* b_out = (const float*)d_in[4];
  float* out = (float*)d_out;

  char* ws = (char*)d_ws;
  u16t* xb    = (u16t*)(ws);
  u16t* wqkvT = (u16t*)(ws + 8388608);
  u16t* woutT = (u16t*)(ws + 14680064);
  u16t* qb    = (u16t*)(ws + 16777216);
  u16t* kb    = (u16t*)(ws + 25165824);
  u16t* vtb   = (u16t*)(ws + 33554432);
  u16t* attnb = (u16t*)(ws + 41943040);

  k_cast_x<<<2048, 256, 0, stream>>>(x, xb, 4194304);
  k_transpose_cast<<<dim3(48, 16), 256, 0, stream>>>(W_qkv, wqkvT, 1024, 3072);
  k_transpose_cast<<<dim3(16, 16), 256, 0, stream>>>(W_out, woutT, 1024, 1024);
  k_gemm_qkv<<<dim3(32, 24), 256, 0, stream>>>(xb, wqkvT, b_qkv, qb, kb, vtb);
  k_attn<<<dim3(16, 32), 256, 0, stream>>>(qb, kb, vtb, attnb);
  k_gemm_out<<<dim3(32, 8), 256, 0, stream>>>(attnb, woutT, b_out, out);
}